// Round 3
// baseline (42.880 us; speedup 1.0000x reference)
//
#include <hip/hip_runtime.h>
#include <math.h>

// Forward kinematics, 6-joint DH chain, B=1048576 elements.
// Strategy: all rotation-sensitive math in float64 so atan2 branch-cut signs
// match a float64 numpy reference (A/C outputs are deg(atan2) near +/-180;
// a sign flip there is a 360-degree error vs a 52.48 threshold).

#define PI_D  3.141592653589793
#define RAD_D (PI_D / 180.0)
#define DEG_D (180.0 / PI_D)
#define TINY_D 1e-6

__global__ __launch_bounds__(256)
void fk6_kernel(const float* __restrict__ theta,
                const float* __restrict__ dh,
                float* __restrict__ out,
                int B)
{
    // Per-block precompute of DH-derived constants (6 double sincos saved per thread).
    __shared__ double s_a[6], s_ca[6], s_sa[6], s_nsd[6], s_cd[6], s_th0[6];
    if (threadIdx.x < 6) {
        const int i = threadIdx.x;
        const double a     = (double)dh[i * 4 + 0];
        const double alpha = (double)dh[i * 4 + 1] * RAD_D;
        const double d     = (double)dh[i * 4 + 2];
        const double th0   = (double)dh[i * 4 + 3];
        const double ca = cos(alpha);
        const double sa = sin(alpha);
        s_a[i]   = a;
        s_ca[i]  = ca;
        s_sa[i]  = sa;
        s_nsd[i] = -sa * d;   // T[1][3]
        s_cd[i]  =  ca * d;   // T[2][3]
        s_th0[i] = th0;
    }
    __syncthreads();

    const long long b = (long long)blockIdx.x * blockDim.x + threadIdx.x;
    if (b >= B) return;

    // theta row: 24 bytes, 8-byte aligned -> three float2 loads.
    const float2* tp = reinterpret_cast<const float2*>(theta + 6ll * b);
    const float2 v01 = tp[0];
    const float2 v23 = tp[1];
    const float2 v45 = tp[2];
    const double th[6] = { (double)v01.x, (double)v01.y,
                           (double)v23.x, (double)v23.y,
                           (double)v45.x, (double)v45.y };

    // Affine 3x4 accumulator M = T0 * T1 * ... * T5 (row 3 is [0,0,0,1]).
    double M[3][4];
    {
        double st, ct;
        sincos((s_th0[0] + th[0]) * RAD_D, &st, &ct);
        const double ca = s_ca[0], sa = s_sa[0];
        M[0][0] = ct;      M[0][1] = -st;     M[0][2] = 0.0;  M[0][3] = s_a[0];
        M[1][0] = st * ca; M[1][1] = ct * ca; M[1][2] = -sa;  M[1][3] = s_nsd[0];
        M[2][0] = st * sa; M[2][1] = ct * sa; M[2][2] = ca;   M[2][3] = s_cd[0];
    }

    #pragma unroll
    for (int i = 1; i < 6; ++i) {
        double st, ct;
        sincos((s_th0[i] + th[i]) * RAD_D, &st, &ct);
        const double ca = s_ca[i], sa = s_sa[i];
        // T_i entries (col 2 of row 0 is always 0):
        const double t00 = ct,      t01 = -st,     t03 = s_a[i];
        const double t10 = st * ca, t11 = ct * ca, t12 = -sa, t13 = s_nsd[i];
        const double t20 = st * sa, t21 = ct * sa, t22 = ca,  t23 = s_cd[i];
        #pragma unroll
        for (int r = 0; r < 3; ++r) {
            const double m0 = M[r][0], m1 = M[r][1], m2 = M[r][2], m3 = M[r][3];
            M[r][0] = m0 * t00 + m1 * t10 + m2 * t20;
            M[r][1] = m0 * t01 + m1 * t11 + m2 * t21;
            M[r][2] =            m1 * t12 + m2 * t22;          // t02 == 0
            M[r][3] = m0 * t03 + m1 * t13 + m2 * t23 + m3;     // t33 == 1
        }
    }

    const double T00 = M[0][0], T01 = M[0][1], T02 = M[0][2];
    const double T10 = M[1][0], T11 = M[1][1], T12 = M[1][2];
    const double T22 = M[2][2];

    // Normal (non-singular) Euler extraction.
    const double An = atan2(-T01, T00) * DEG_D;
    double sA, cA;
    sincos(An * RAD_D, &sA, &cA);
    const double Bn = atan2(T02, cA * T00 - sA * T01) * DEG_D;
    const double Cn = atan2(-T12, T22) * DEG_D;

    double A = An, Bd = Bn, C = Cn;
    // Gimbal-lock branch (essentially never taken for random inputs;
    // wave-uniformly skipped).
    if (fabs(T12) <= TINY_D && fabs(T22) <= TINY_D) {
        // _divide_no_nan(x, 1.0) == x
        Bd = atan2(T02, T22) * DEG_D;
        A  = atan2(T10, T11) * DEG_D;
        C  = 0.0;
    }

    // Output row: [x, y, z, A, B, C], 24 bytes, 8-byte aligned -> three float2 stores.
    float2* op = reinterpret_cast<float2*>(out + 6ll * b);
    op[0] = make_float2((float)M[0][3], (float)M[1][3]);
    op[1] = make_float2((float)M[2][3], (float)A);
    op[2] = make_float2((float)Bd,      (float)C);
}

extern "C" void kernel_launch(void* const* d_in, const int* in_sizes, int n_in,
                              void* d_out, int out_size, void* d_ws, size_t ws_size,
                              hipStream_t stream) {
    const float* theta = (const float*)d_in[0];   // (B, 6) f32
    const float* dh    = (const float*)d_in[1];   // (6, 4) f32
    float* out = (float*)d_out;                   // (B, 6) f32

    const int B = in_sizes[0] / 6;
    const int block = 256;
    const int grid = (B + block - 1) / block;
    fk6_kernel<<<grid, block, 0, stream>>>(theta, dh, out, B);
}

// Round 4
// 25.182 us; speedup vs baseline: 1.7028x; 1.7028x over previous
//
#include <hip/hip_runtime.h>
#include <math.h>

// Forward kinematics, 6-joint DH chain, B=1048576.
// f64 rotation chain (atan2 branch-cut sign safety vs numpy ref), but with:
//  - custom f64 sincos taking DEGREES (exact range reduction, Cephes polys)
//  - f32 atan2 on f64-rounded args (sign of (float)x == sign of x_f64)
//  - B_n via hypot identity: cA*T00 - sA*T01 == sqrt(T00^2+T01^2) >= 0

#define PI_D   3.141592653589793
#define RAD_D  (PI_D / 180.0)
#define DEG_F  57.29577951308232f
#define TINY_D 1e-6

// sin/cos of (xdeg degrees). Exact quadrant reduction in degrees, then
// Cephes minimax polynomials on |r| <= pi/4 (~1ulp f64).
__device__ __forceinline__ void sincos_deg(double xdeg, double* s, double* c)
{
    const double qf = rint(xdeg * (1.0 / 90.0));
    const double r  = fma(qf, -90.0, xdeg) * RAD_D;   // |r| <= pi/4 (radians)
    const int q = ((int)qf) & 3;

    const double z = r * r;

    double sp = 1.58962301576546568060e-10;
    sp = fma(sp, z, -2.50507477628578072866e-8);
    sp = fma(sp, z,  2.75573136213857245213e-6);
    sp = fma(sp, z, -1.98412698295895385996e-4);
    sp = fma(sp, z,  8.33333333332211858878e-3);
    sp = fma(sp, z, -1.66666666666666307295e-1);
    const double sr = fma(r * z, sp, r);              // sin(r)

    double cp = -1.13585365213876817300e-11;
    cp = fma(cp, z,  2.08757008419747316778e-9);
    cp = fma(cp, z, -2.75573141792967388112e-7);
    cp = fma(cp, z,  2.48015872888517179954e-5);
    cp = fma(cp, z, -1.38888888888730564116e-3);
    cp = fma(cp, z,  4.16666666666665929218e-2);
    const double cr = fma(z * z, cp, fma(z, -0.5, 1.0)); // cos(r)

    // quadrant: 0:(s,c)=(sr,cr) 1:(cr,-sr) 2:(-sr,-cr) 3:(-cr,sr)
    double ss = (q & 1) ? cr : sr;
    double cc = (q & 1) ? sr : cr;
    ss = (q & 2)        ? -ss : ss;   // q in {2,3}
    cc = ((q + 1) & 2)  ? -cc : cc;   // q in {1,2}
    *s = ss; *c = cc;
}

__global__ __launch_bounds__(256)
void fk6_kernel(const float* __restrict__ theta,
                const float* __restrict__ dh,
                float* __restrict__ out,
                int B)
{
    // Per-block DH-derived constants.
    __shared__ double s_a[6], s_ca[6], s_sa[6], s_nsd[6], s_cd[6], s_th0[6];
    if (threadIdx.x < 6) {
        const int i = threadIdx.x;
        const double a         = (double)dh[i * 4 + 0];
        const double alpha_deg = (double)dh[i * 4 + 1];
        const double d         = (double)dh[i * 4 + 2];
        const double th0       = (double)dh[i * 4 + 3];
        double sa, ca;
        sincos_deg(alpha_deg, &sa, &ca);
        s_a[i]   = a;
        s_ca[i]  = ca;
        s_sa[i]  = sa;
        s_nsd[i] = -sa * d;
        s_cd[i]  =  ca * d;
        s_th0[i] = th0;
    }
    __syncthreads();

    const long long b = (long long)blockIdx.x * blockDim.x + threadIdx.x;
    if (b >= B) return;

    const float2* tp = reinterpret_cast<const float2*>(theta + 6ll * b);
    const float2 v01 = tp[0];
    const float2 v23 = tp[1];
    const float2 v45 = tp[2];
    const double th[6] = { (double)v01.x, (double)v01.y,
                           (double)v23.x, (double)v23.y,
                           (double)v45.x, (double)v45.y };

    // All 6 joint sincos upfront (independent -> ILP hides poly latency).
    double st[6], ct[6];
    #pragma unroll
    for (int i = 0; i < 6; ++i)
        sincos_deg(s_th0[i] + th[i], &st[i], &ct[i]);

    // Affine 3x4 accumulator M = T0 * T1 * ... * T5.
    double M[3][4];
    {
        const double ca = s_ca[0], sa = s_sa[0];
        M[0][0] = ct[0];      M[0][1] = -st[0];     M[0][2] = 0.0;  M[0][3] = s_a[0];
        M[1][0] = st[0] * ca; M[1][1] = ct[0] * ca; M[1][2] = -sa;  M[1][3] = s_nsd[0];
        M[2][0] = st[0] * sa; M[2][1] = ct[0] * sa; M[2][2] = ca;   M[2][3] = s_cd[0];
    }

    #pragma unroll
    for (int i = 1; i < 6; ++i) {
        const double ca = s_ca[i], sa = s_sa[i];
        const double t00 = ct[i],      t01 = -st[i],     t03 = s_a[i];
        const double t10 = st[i] * ca, t11 = ct[i] * ca, t12 = -sa, t13 = s_nsd[i];
        const double t20 = st[i] * sa, t21 = ct[i] * sa, t22 = ca,  t23 = s_cd[i];
        #pragma unroll
        for (int r = 0; r < 3; ++r) {
            const double m0 = M[r][0], m1 = M[r][1], m2 = M[r][2], m3 = M[r][3];
            M[r][0] = m0 * t00 + m1 * t10 + m2 * t20;
            M[r][1] = m0 * t01 + m1 * t11 + m2 * t21;
            M[r][2] =            m1 * t12 + m2 * t22;         // t02 == 0
            M[r][3] = m0 * t03 + m1 * t13 + m2 * t23 + m3;    // t33 == 1
        }
    }

    const double T00 = M[0][0], T01 = M[0][1], T02 = M[0][2];
    const double T10 = M[1][0], T11 = M[1][1], T12 = M[1][2];
    const double T22 = M[2][2];

    // f32 atan2 on f64-rounded args: sign((float)x) == sign(x_f64), so the
    // branch-cut side matches the f64 chain; value error ~2e-5 deg.
    const float t00f = (float)T00, t01f = (float)T01, t02f = (float)T02;
    const float t12f = (float)T12, t22f = (float)T22;

    const float An = atan2f(-t01f, t00f) * DEG_F;
    // cA*T00 - sA*T01 == sqrt(T00^2 + T01^2) >= 0  -> no branch cut for B.
    const float r01 = sqrtf(fmaf(t00f, t00f, t01f * t01f));
    const float Bn = atan2f(t02f, r01) * DEG_F;
    const float Cn = atan2f(-t12f, t22f) * DEG_F;

    float A = An, Bd = Bn, C = Cn;
    // Gimbal-lock branch (measure-zero for random inputs; wave-uniform skip).
    if (fabs(T12) <= TINY_D && fabs(T22) <= TINY_D) {
        Bd = atan2f(t02f, t22f) * DEG_F;
        A  = atan2f((float)T10, (float)T11) * DEG_F;
        C  = 0.0f;
    }

    float2* op = reinterpret_cast<float2*>(out + 6ll * b);
    op[0] = make_float2((float)M[0][3], (float)M[1][3]);
    op[1] = make_float2((float)M[2][3], A);
    op[2] = make_float2(Bd, C);
}

extern "C" void kernel_launch(void* const* d_in, const int* in_sizes, int n_in,
                              void* d_out, int out_size, void* d_ws, size_t ws_size,
                              hipStream_t stream) {
    const float* theta = (const float*)d_in[0];   // (B, 6) f32
    const float* dh    = (const float*)d_in[1];   // (6, 4) f32
    float* out = (float*)d_out;                   // (B, 6) f32

    const int B = in_sizes[0] / 6;
    const int block = 256;
    const int grid = (B + block - 1) / block;
    fk6_kernel<<<grid, block, 0, stream>>>(theta, dh, out, B);
}

// Round 5
// 22.678 us; speedup vs baseline: 1.8908x; 1.1104x over previous
//
#include <hip/hip_runtime.h>
#include <math.h>

// Forward kinematics, 6-joint DH chain, B=1048576.
// Fast path: full f32 chain (custom degree-input sincos, exact quadrant
// reduction). Safety: lanes where an atan2 branch-cut / gimbal-branch
// decision is within 50x of f32 noise are recomputed with the (previously
// passing) f64 path — exec-masked, ~0.03% of lanes, ~2% of waves.

#define PI_D   3.141592653589793
#define RAD_D  (PI_D / 180.0)
#define RAD_F  0.017453292519943295f
#define DEG_F  57.29577951308232f
#define TINY_D 1e-6

// ---------- f64 sincos of degrees (Cephes, ~1ulp) ----------
__device__ __forceinline__ void sincos_deg(double xdeg, double* s, double* c)
{
    const double qf = rint(xdeg * (1.0 / 90.0));
    const double r  = fma(qf, -90.0, xdeg) * RAD_D;
    const int q = ((int)qf) & 3;
    const double z = r * r;

    double sp = 1.58962301576546568060e-10;
    sp = fma(sp, z, -2.50507477628578072866e-8);
    sp = fma(sp, z,  2.75573136213857245213e-6);
    sp = fma(sp, z, -1.98412698295895385996e-4);
    sp = fma(sp, z,  8.33333333332211858878e-3);
    sp = fma(sp, z, -1.66666666666666307295e-1);
    const double sr = fma(r * z, sp, r);

    double cp = -1.13585365213876817300e-11;
    cp = fma(cp, z,  2.08757008419747316778e-9);
    cp = fma(cp, z, -2.75573141792967388112e-7);
    cp = fma(cp, z,  2.48015872888517179954e-5);
    cp = fma(cp, z, -1.38888888888730564116e-3);
    cp = fma(cp, z,  4.16666666666665929218e-2);
    const double cr = fma(z * z, cp, fma(z, -0.5, 1.0));

    double ss = (q & 1) ? cr : sr;
    double cc = (q & 1) ? sr : cr;
    ss = (q & 2)       ? -ss : ss;
    cc = ((q + 1) & 2) ? -cc : cc;
    *s = ss; *c = cc;
}

// ---------- f32 sincos of degrees (Cephes f32, ~1ulp f32) ----------
__device__ __forceinline__ void sincosf_deg(float xdeg, float* s, float* c)
{
    const float qf = rintf(xdeg * (1.0f / 90.0f));
    const float r  = fmaf(qf, -90.0f, xdeg) * RAD_F;
    const int q = ((int)qf) & 3;
    const float z = r * r;

    float sp = -1.9515295891e-4f;
    sp = fmaf(sp, z,  8.3321608736e-3f);
    sp = fmaf(sp, z, -1.6666654611e-1f);
    const float sr = fmaf(r * z, sp, r);

    float cp =  2.443315711809948e-5f;
    cp = fmaf(cp, z, -1.388731625493765e-3f);
    cp = fmaf(cp, z,  4.166664568298827e-2f);
    const float cr = fmaf(z * z, cp, fmaf(z, -0.5f, 1.0f));

    float ss = (q & 1) ? cr : sr;
    float cc = (q & 1) ? sr : cr;
    ss = (q & 2)       ? -ss : ss;
    cc = ((q + 1) & 2) ? -cc : cc;
    *s = ss; *c = cc;
}

__global__ __launch_bounds__(256)
void fk6_kernel(const float* __restrict__ theta,
                const float* __restrict__ dh,
                float* __restrict__ out,
                int B)
{
    // DH-derived constants: f64 (slow path) + f32 copies (fast path).
    __shared__ double s_a[6], s_ca[6], s_sa[6], s_nsd[6], s_cd[6], s_th0[6];
    __shared__ float  f_a[6], f_ca[6], f_sa[6], f_nsd[6], f_cd[6], f_th0[6];
    if (threadIdx.x < 6) {
        const int i = threadIdx.x;
        const double a   = (double)dh[i * 4 + 0];
        const double alp = (double)dh[i * 4 + 1];
        const double d   = (double)dh[i * 4 + 2];
        const double th0 = (double)dh[i * 4 + 3];
        double sa, ca;
        sincos_deg(alp, &sa, &ca);
        s_a[i] = a;  s_ca[i] = ca;  s_sa[i] = sa;
        s_nsd[i] = -sa * d;  s_cd[i] = ca * d;  s_th0[i] = th0;
        f_a[i] = (float)a;  f_ca[i] = (float)ca;  f_sa[i] = (float)sa;
        f_nsd[i] = (float)(-sa * d);  f_cd[i] = (float)(ca * d);  f_th0[i] = (float)th0;
    }
    __syncthreads();

    const long long b = (long long)blockIdx.x * blockDim.x + threadIdx.x;
    if (b >= B) return;

    const float2* tp = reinterpret_cast<const float2*>(theta + 6ll * b);
    const float2 v01 = tp[0];
    const float2 v23 = tp[1];
    const float2 v45 = tp[2];
    const float thf[6] = { v01.x, v01.y, v23.x, v23.y, v45.x, v45.y };

    // ---------------- fast path: f32 ----------------
    float st[6], ct[6];
    #pragma unroll
    for (int i = 0; i < 6; ++i)
        sincosf_deg(f_th0[i] + thf[i], &st[i], &ct[i]);

    float M[3][4];
    {
        const float ca = f_ca[0], sa = f_sa[0];
        M[0][0] = ct[0];      M[0][1] = -st[0];     M[0][2] = 0.0f; M[0][3] = f_a[0];
        M[1][0] = st[0] * ca; M[1][1] = ct[0] * ca; M[1][2] = -sa;  M[1][3] = f_nsd[0];
        M[2][0] = st[0] * sa; M[2][1] = ct[0] * sa; M[2][2] = ca;   M[2][3] = f_cd[0];
    }
    #pragma unroll
    for (int i = 1; i < 6; ++i) {
        const float ca = f_ca[i], sa = f_sa[i];
        const float t00 = ct[i],      t01 = -st[i],     t03 = f_a[i];
        const float t10 = st[i] * ca, t11 = ct[i] * ca, t12 = -sa, t13 = f_nsd[i];
        const float t20 = st[i] * sa, t21 = ct[i] * sa, t22 = ca,  t23 = f_cd[i];
        #pragma unroll
        for (int r = 0; r < 3; ++r) {
            const float m0 = M[r][0], m1 = M[r][1], m2 = M[r][2], m3 = M[r][3];
            M[r][0] = m0 * t00 + m1 * t10 + m2 * t20;
            M[r][1] = m0 * t01 + m1 * t11 + m2 * t21;
            M[r][2] =            m1 * t12 + m2 * t22;
            M[r][3] = m0 * t03 + m1 * t13 + m2 * t23 + m3;
        }
    }

    const float T00 = M[0][0], T01 = M[0][1], T02 = M[0][2];
    const float T12 = M[1][2], T22 = M[2][2];

    float ox = M[0][3], oy = M[1][3], oz = M[2][3];
    float A  = atan2f(-T01, T00) * DEG_F;
    // cA*T00 - sA*T01 == sqrt(T00^2+T01^2) >= 0  (unit row) -> no branch cut.
    float Bd = atan2f(T02, sqrtf(fmaf(T00, T00, T01 * T01))) * DEG_F;
    float C  = atan2f(-T12, T22) * DEG_F;

    // ---------------- safety net: flag decisions within 50x of f32 noise ----
    const bool risky = (fabsf(T01) < 1e-4f) | (fabsf(T12) < 1e-4f) |
                       (fmaf(T00, T00, T01 * T01) < 1e-6f) |
                       (fmaf(T12, T12, T22 * T22) < 1e-6f);

    if (__builtin_expect(risky, 0)) {
        // Exact replica of the previously-passing f64 path.
        double dst[6], dct[6];
        #pragma unroll
        for (int i = 0; i < 6; ++i)
            sincos_deg(s_th0[i] + (double)thf[i], &dst[i], &dct[i]);

        double D[3][4];
        {
            const double ca = s_ca[0], sa = s_sa[0];
            D[0][0] = dct[0];      D[0][1] = -dst[0];     D[0][2] = 0.0; D[0][3] = s_a[0];
            D[1][0] = dst[0] * ca; D[1][1] = dct[0] * ca; D[1][2] = -sa; D[1][3] = s_nsd[0];
            D[2][0] = dst[0] * sa; D[2][1] = dct[0] * sa; D[2][2] = ca;  D[2][3] = s_cd[0];
        }
        #pragma unroll
        for (int i = 1; i < 6; ++i) {
            const double ca = s_ca[i], sa = s_sa[i];
            const double t00 = dct[i],      t01 = -dst[i],     t03 = s_a[i];
            const double t10 = dst[i] * ca, t11 = dct[i] * ca, t12 = -sa, t13 = s_nsd[i];
            const double t20 = dst[i] * sa, t21 = dct[i] * sa, t22 = ca,  t23 = s_cd[i];
            #pragma unroll
            for (int r = 0; r < 3; ++r) {
                const double m0 = D[r][0], m1 = D[r][1], m2 = D[r][2], m3 = D[r][3];
                D[r][0] = m0 * t00 + m1 * t10 + m2 * t20;
                D[r][1] = m0 * t01 + m1 * t11 + m2 * t21;
                D[r][2] =            m1 * t12 + m2 * t22;
                D[r][3] = m0 * t03 + m1 * t13 + m2 * t23 + m3;
            }
        }
        const float d00 = (float)D[0][0], d01 = (float)D[0][1], d02 = (float)D[0][2];
        const float d12 = (float)D[1][2], d22 = (float)D[2][2];

        ox = (float)D[0][3]; oy = (float)D[1][3]; oz = (float)D[2][3];
        A  = atan2f(-d01, d00) * DEG_F;
        Bd = atan2f(d02, sqrtf(fmaf(d00, d00, d01 * d01))) * DEG_F;
        C  = atan2f(-d12, d22) * DEG_F;
        if (fabs(D[1][2]) <= TINY_D && fabs(D[2][2]) <= TINY_D) {
            Bd = atan2f(d02, d22) * DEG_F;
            A  = atan2f((float)D[1][0], (float)D[1][1]) * DEG_F;
            C  = 0.0f;
        }
    }

    float2* op = reinterpret_cast<float2*>(out + 6ll * b);
    op[0] = make_float2(ox, oy);
    op[1] = make_float2(oz, A);
    op[2] = make_float2(Bd, C);
}

extern "C" void kernel_launch(void* const* d_in, const int* in_sizes, int n_in,
                              void* d_out, int out_size, void* d_ws, size_t ws_size,
                              hipStream_t stream) {
    const float* theta = (const float*)d_in[0];   // (B, 6) f32
    const float* dh    = (const float*)d_in[1];   // (6, 4) f32
    float* out = (float*)d_out;                   // (B, 6) f32

    const int B = in_sizes[0] / 6;
    const int block = 256;
    const int grid = (B + block - 1) / block;
    fk6_kernel<<<grid, block, 0, stream>>>(theta, dh, out, B);
}